// Round 14
// baseline (207.164 us; speedup 1.0000x reference)
//
#include <hip/hip_runtime.h>

typedef unsigned short u16;
typedef unsigned int   u32;

typedef short shortx8   __attribute__((ext_vector_type(8)));
typedef float floatx4   __attribute__((ext_vector_type(4)));
typedef float floatx16  __attribute__((ext_vector_type(16)));
typedef u32   uintx4    __attribute__((ext_vector_type(4)));

typedef u32     u32a     __attribute__((may_alias));
typedef uintx4  uintx4a  __attribute__((may_alias));
typedef shortx8 shortx8a __attribute__((may_alias));

// accurate round-to-nearest-even (weights)
__device__ __forceinline__ u16 f2bf(float f){
  union { float f; u32 i; } v; v.f = f;
  return (u16)((v.i + 0x7fffu + ((v.i >> 16) & 1u)) >> 16);
}
// fast round-half-up (scalar hot path; max 0.5 ulp)
__device__ __forceinline__ u16 f2bf_fast(float f){
  union { float f; u32 i; } v; v.f = f;
  return (u16)((v.i + 0x8000u) >> 16);
}
// pack two bf16 via v_perm (3 VALU ops) — fallback
__device__ __forceinline__ u32 pack2(float lo, float hi){
  union { float f; u32 i; } a, b; a.f = lo; b.f = hi;
  return __builtin_amdgcn_perm(b.i + 0x8000u, a.i + 0x8000u, 0x07060302u);
}
// packed f32->bf16 convert: 1 VALU op on gfx950 (v_cvt_pk_bf16_f32), RNE
__device__ __forceinline__ u32 cvtpk2(float lo, float hi){
#if __has_builtin(__builtin_amdgcn_cvt_pk_bf16_f32)
  auto pv = __builtin_amdgcn_cvt_pk_bf16_f32(lo, hi);
  if constexpr (sizeof(pv) == 4){
    u32 out; __builtin_memcpy(&out, &pv, 4); return out;
  } else {
    return pack2(lo, hi);
  }
#else
  return pack2(lo, hi);
#endif
}
__device__ __forceinline__ float lrelu(float v){ return fmaxf(v, 0.01f*v); }

// ---------------------------------------------------------------------------
// Kernel 1: fused conv1 (VALU) -> conv2 (MFMA 32x32x16) -> conv3 (MFMA
// 16x16x32), SOFTWARE-PIPELINED across the 8 (bb x tt) phases with
// double-buffered per-pair h1/h2 LDS slots:
//   body(i) = [conv1(i+1); conv2(i); conv3(i-1)]; ONE barrier per phase
// (9 vs 16 per block). Safety: conv2(i) reads h1[i&1] written >=1 barrier
// earlier; conv3(i-1) reads h2[(i-1)&1] written 1 barrier earlier; every
// WAR pair (conv1(i+1) vs conv2(i-1) on h1[(i+1)&1]; conv2(i) vs conv3(i-2)
// on h2[i&1]) is separated by >=1 barrier. Round-13 lesson: the ~27%
// non-issue residue is barrier drain — this halves it and gives each
// inter-barrier section 3 independent streams (VALU + 2 MFMA chains).
// Emits Xb during staging; absorbs prep (256 elements/block, exact:
// 3840 x 256 = 983,040). grid (16 t-pairs, 16 b-groups, 15 nodes),
// block 256 (4 waves = 2 pairs).
// ---------------------------------------------------------------------------
__global__ void __launch_bounds__(256, 4) fused_conv(
    const float* __restrict__ X,
    const float* __restrict__ w1, const float* __restrict__ b1,
    const float* __restrict__ w2, const float* __restrict__ b2,
    const float* __restrict__ w3, const float* __restrict__ b3,
    u16* __restrict__ h3p, u16* __restrict__ Xb,
    const float* __restrict__ lw, u16* __restrict__ lwb,
    const float* __restrict__ gw, u16* __restrict__ gwp){
  const int tid  = threadIdx.x;
  const int node = blockIdx.z;
  const int p0   = blockIdx.x * 120;
  const int b0   = blockIdx.y * 8;

  __shared__ __attribute__((aligned(16))) u16 sH1[2*2*1632]; // [pair][buf][68*24]
  __shared__ __attribute__((aligned(16))) u16 sH2[2*2*2720]; // [pair][buf][68*40]
  __shared__ __attribute__((aligned(16))) u16 sW2f[2560];    // [tap][kh][oc32][j8]
  __shared__ __attribute__((aligned(16))) u16 sW3f[160];     // [tap][ic32]
  __shared__ u16 sXb[8*136];                                 // bf16 X window (120+16)
  __shared__ float sW1[80], sB1[16], sB2[32];

  // ---- distributed prep: 256 elements per block, exact coverage ----
  {
    const int bid = blockIdx.x + 16*(blockIdx.y + 16*blockIdx.z);  // 0..3839
    int gid = bid*256 + tid;                   // 0..983039
    if (gid < 491520){
      lwb[gid] = f2bf(lw[gid]);                // lin1_w: 256*1920 elements
    } else {
      int g2 = gid - 491520;                   // 0..491519 (gwp elements)
      int row = g2 / 1920;                     // 0..255
      int col = g2 - row*1920;
      gwp[g2] = (col < 1908) ? f2bf(gw[row*1908 + col]) : (u16)0;
    }
  }

  // ---- staging ----
  {
    const int bls = tid >> 5, i0 = tid & 31;   // 8 batches x 32 threads
    const float* xrow = X  + (size_t)((b0 + bls)*15 + node)*1920;
    u16*        xbrow = Xb + (size_t)((b0 + bls)*15 + node)*1920;
    #pragma unroll
    for (int u = 0; u < 5; ++u){
      int i = i0 + 32*u;
      if (i < 136){
        int g = p0 + i;
        float xv = (g < 1920) ? xrow[g] : 0.f;
        u16 xb = f2bf_fast(xv);
        sXb[bls*136 + i] = xb;
        if (i < 120) xbrow[g] = xb;   // i<120 => g<1920 always
      }
    }
    // w2 into 32x32 A-frag order: idx = ((tap*2 + kh)*32 + oc)*8 + j
    #pragma unroll
    for (int u = 0; u < 10; ++u){
      int d = tid + 256*u;
      int j = d & 7, oc = (d >> 3) & 31, kh = (d >> 8) & 1, tap = d >> 9; // 0..4
      sW2f[d] = f2bf(w2[node*2560 + (oc*16 + kh*8 + j)*5 + tap]);
    }
    if (tid < 160){
      int icc = tid / 5, tp = tid - 5*icc;
      sW3f[tp*32 + icc] = f2bf(w3[node*160 + tid]);
    }
    if (tid < 80) sW1[tid] = w1[node*80 + tid];
    if (tid < 16) sB1[tid] = b1[node*16 + tid];
    if (tid < 32) sB2[tid] = b2[node*32 + tid];
  }

  const int w = tid >> 6, lane = tid & 63;
  const int pw = w >> 1, ph = w & 1;          // pair index (0..1) / pair half
  const int m = lane & 15, quad = lane >> 4;  // 16x16 roles
  const int t32 = lane & 31, kh = lane >> 5;  // 32x32 roles (kh = k-half)

  // zero tail rows 64..67 of BOTH h2 buffers of this pair (conv2 writes
  // rows 0..63; conv3 reads up to 67); ordered before use by barriers.
  {
    const int base = tid >> 7;      // unused; keep simple per-pair loop below
    (void)base;
    for (int i = lane + ph*64; i < 320; i += 128){
      int buf = i / 160, off = i - buf*160;
      sH2[(pw*2 + buf)*2720 + 2560 + off] = 0;
    }
  }
  __syncthreads();   // staging + tail-zero complete

  // conv2 A-frags (32x32x16): A[m=oc=lane&31][k=kh*8+j]
  shortx8 a2t[5];
  #pragma unroll
  for (int tap = 0; tap < 5; ++tap)
    a2t[tap] = *(const shortx8a*)&sW2f[((tap*2 + kh)*32 + t32)*8];

  // conv2 bias per accumulator reg: row(oc) = (r&3) + 8*(r>>2) + 4*kh
  float biasr[16];
  #pragma unroll
  for (int r = 0; r < 16; ++r)
    biasr[r] = sB2[(r&3) + 8*(r>>2) + 4*kh];

  // conv3 A-frags (16x16x32): only row m=0 nonzero
  shortx8 a3[5];
  {
    const shortx8 zv = {0,0,0,0,0,0,0,0};
    #pragma unroll
    for (int tp = 0; tp < 5; ++tp){
      shortx8 t = *(const shortx8a*)&sW3f[tp*32 + quad*8];
      a3[tp] = (m == 0) ? t : zv;
    }
  }
  const float b3v = b3[node];

  // conv1 per-lane role: 8 ic-pairs x 16 pair-wide t-chunks of 5
  const int c1ic = (lane & 7)*2;
  const int cc   = (lane >> 3) + ph*8;   // 0..15
  const int t0c  = cc*5;                 // 0,5,...,75 (chunks >=68 idle)
  float wa[5], wb[5];
  #pragma unroll
  for (int k = 0; k < 5; ++k){ wa[k] = sW1[c1ic*5 + k]; wb[k] = sW1[c1ic*5 + 5 + k]; }
  const float ba = sB1[c1ic], bbv = sB1[c1ic + 1];

  // phase idx -> bb = idx>>1, tt = idx&1, buf = idx&1
  auto do_conv1 = [&](int idx){
    if (t0c >= 68) return;
    const int bb = idx >> 1, tt = idx & 1, buf = idx & 1;
    const int bl = pw + bb*2;
    const u16* xr = sXb + bl*136 + tt*60;
    u16* h1d = sH1 + (pw*2 + buf)*1632;
    union { u32 i; float f; } cv;
    float xw[5];
    #pragma unroll
    for (int k = 0; k < 4; ++k){ cv.i = ((u32)xr[t0c+k]) << 16; xw[k] = cv.f; }
    #pragma unroll
    for (int i = 0; i < 5; ++i){
      const int t = t0c + i;
      cv.i = ((u32)xr[t + 4]) << 16; xw[4] = cv.f;   // max idx 60+73=133 < 136
      float va = ba  + wa[0]*xw[0] + wa[1]*xw[1] + wa[2]*xw[2] + wa[3]*xw[3] + wa[4]*xw[4];
      float vb = bbv + wb[0]*xw[0] + wb[1]*xw[1] + wb[2]*xw[2] + wb[3]*xw[3] + wb[4]*xw[4];
      va = lrelu(va); vb = lrelu(vb);
      if (t < 68) *(u32a*)(h1d + t*24 + c1ic) = cvtpk2(va, vb);
      xw[0] = xw[1]; xw[1] = xw[2]; xw[2] = xw[3]; xw[3] = xw[4];
    }
  };

  auto do_conv2 = [&](int idx){
    const int buf = idx & 1;
    const u16* h1s = sH1 + (pw*2 + buf)*1632;
    u16*       h2d = sH2 + (pw*2 + buf)*2720;
    const int t0 = ph*32;
    floatx16 acc;
    #pragma unroll
    for (int r = 0; r < 16; ++r) acc[r] = biasr[r];
    #pragma unroll
    for (int tap = 0; tap < 5; ++tap){
      shortx8 bfr = *(const shortx8a*)(h1s + (t0 + t32 + tap)*24 + kh*8);
      acc = __builtin_amdgcn_mfma_f32_32x32x16_bf16(a2t[tap], bfr, acc, 0, 0, 0);
    }
    // D: col(t)=lane&31, row(oc)=(r&3)+8*(r>>2)+4*kh; r-pairs = oc pairs
    u16* dst = h2d + (t0 + t32)*40;
    #pragma unroll
    for (int r = 0; r < 16; r += 2){
      float v0 = lrelu(acc[r]);
      float v1 = lrelu(acc[r+1]);
      const int oc0 = (r&3) + 8*(r>>2) + 4*kh;
      *(u32a*)(dst + oc0) = cvtpk2(v0, v1);
    }
  };

  auto do_conv3 = [&](int idx){
    const int bb = idx >> 1, tt = idx & 1, buf = idx & 1;
    const int bl = pw + bb*2;
    const int p  = p0 + tt*60;
    const int rg = (b0 + bl)*15 + node;
    const u16* h2s = sH2 + (pw*2 + buf)*2720;
    #pragma unroll
    for (int i = 0; i < 2; ++i){
      const int nt = 2*ph + i;
      floatx4 acc3 = {0.f,0.f,0.f,0.f};
      if (lane < 16) acc3[0] = b3v;
      #pragma unroll
      for (int tp = 0; tp < 5; ++tp){
        shortx8 bfr = *(const shortx8a*)(h2s + (nt*16 + m + tp)*40 + quad*8);
        acc3 = __builtin_amdgcn_mfma_f32_16x16x32_bf16(a3[tp], bfr, acc3, 0, 0, 0);
      }
      const int tl = nt*16 + lane;
      if (lane < 16 && tl < 60){
        const int t3 = p + tl;           // max 15*120+60+59 = 1919 < 1920
        float v = lrelu(acc3[0]);
        h3p[(size_t)rg*1920 + t3] = (t3 < 1908) ? f2bf_fast(v) : (u16)0;
      }
    }
  };

  // ---- pipelined phase loop: one barrier per phase ----
  do_conv1(0);
  __syncthreads();
  #pragma unroll
  for (int i = 0; i < 8; ++i){
    if (i < 7) do_conv1(i + 1);
    do_conv2(i);
    if (i > 0) do_conv3(i - 1);
    __syncthreads();
  }
  do_conv3(7);
}

// ---------------------------------------------------------------------------
// Kernel 2: NT GEMM  O[1920][256] = A[1920][1920] * B[256][1920]^T (full K,
// plain stores). grid (30,4,2): z = job (0: Xb*lwb->l1, 1: h3p*gwp->xl).
// K-step 64; LDS stride 88 u16. Block (0,0,0) also zeroes the 30KB
// GraphNorm stats buffer (gS/gS2) consumed by gcn_agg/finalize.
// ---------------------------------------------------------------------------
__global__ void __launch_bounds__(256) gemm_nt(
    const u16* __restrict__ A0, const u16* __restrict__ B0, float* __restrict__ O0,
    const u16* __restrict__ A1, const u16* __restrict__ B1, float* __restrict__ O1,
    float* __restrict__ gZ){
  const int job = blockIdx.z;
  const u16* A; const u16* Bm; float* O;
  if (job == 0){ A = A0; Bm = B0; O = O0; } else { A = A1; Bm = B1; O = O1; }
  __shared__ __attribute__((aligned(16))) u16 sA[64*88];
  __shared__ __attribute__((aligned(16))) u16 sB[64*88];
  const int tid = threadIdx.x;
  if (blockIdx.x == 0 && blockIdx.y == 0 && job == 0){
    #pragma unroll
    for (int u = 0; u < 30; ++u) gZ[tid + 256*u] = 0.f;
  }
  const int m0 = blockIdx.x*64, n0 = blockIdx.y*64;
  const int row = tid >> 2, kc = tid & 3;
  const int w = tid >> 6, lane = tid & 63;
  const int m = lane & 15, quad = lane >> 4;
  const int mo = (w & 1)*32, no = (w >> 1)*32;
  floatx4 acc[2][2];
  #pragma unroll
  for (int i = 0; i < 2; ++i)
    #pragma unroll
    for (int j = 0; j < 2; ++j)
      #pragma unroll
      for (int r = 0; r < 4; ++r) acc[i][j][r] = 0.f;

  const u16* ap = A  + (size_t)(m0 + row)*1920 + kc*8;
  const u16* bp = Bm + (size_t)(n0 + row)*1920 + kc*8;
  for (int kt = 0; kt < 30; ++kt){
    uintx4 va0 = *(const uintx4a*)ap;
    uintx4 va1 = *(const uintx4a*)(ap + 32);
    uintx4 vb0 = *(const uintx4a*)bp;
    uintx4 vb1 = *(const uintx4a*)(bp + 32);
    ap += 64; bp += 64;
    *(uintx4a*)&sA[row*88 + kc*8]      = va0;
    *(uintx4a*)&sA[row*88 + 32 + kc*8] = va1;
    *(uintx4a*)&sB[row*88 + kc*8]      = vb0;
    *(uintx4a*)&sB[row*88 + 32 + kc*8] = vb1;
    __syncthreads();
    #pragma unroll
    for (int ks = 0; ks < 64; ks += 32){
      const shortx8 af0 = *(const shortx8a*)&sA[(mo      + m)*88 + ks + quad*8];
      const shortx8 af1 = *(const shortx8a*)&sA[(mo + 16 + m)*88 + ks + quad*8];
      const shortx8 bf0 = *(const shortx8a*)&sB[(no      + m)*88 + ks + quad*8];
      const shortx8 bf1 = *(const shortx8a*)&sB[(no + 16 + m)*88 + ks + quad*8];
      acc[0][0] = __builtin_amdgcn_mfma_f32_16x16x32_bf16(af0, bf0, acc[0][0], 0, 0, 0);
      acc[0][1] = __builtin_amdgcn_mfma_f32_16x16x32_bf16(af0, bf1, acc[0][1], 0, 0, 0);
      acc[1][0] = __builtin_amdgcn_mfma_f32_16x16x32_bf16(af1, bf0, acc[1][0], 0, 0, 0);
      acc[1][1] = __builtin_amdgcn_mfma_f32_16x16x32_bf16(af1, bf1, acc[1][1], 0, 0, 0);
    }
    __syncthreads();
  }
  #pragma unroll
  for (int mi = 0; mi < 2; ++mi)
    #pragma unroll
    for (int ni = 0; ni < 2; ++ni)
      #pragma unroll
      for (int r = 0; r < 4; ++r){
        int rr = m0 + mo + mi*16 + quad*4 + r;
        int cc = n0 + no + ni*16 + m;
        O[(size_t)rr*256 + cc] = acc[mi][ni][r];
      }
}

// ---------------------------------------------------------------------------
// Kernel 3: GCN aggregation + bias, plus per-(n,c) GraphNorm stat
// accumulation (atomicAdd of T and T^2 into gS/gS2, zeroed by gemm_nt).
// ---------------------------------------------------------------------------
__global__ void __launch_bounds__(256) gcn_agg(
    const float* __restrict__ xl, const int* __restrict__ ei,
    const float* __restrict__ ew, const float* __restrict__ gcn_b,
    float* __restrict__ Tpre, float* __restrict__ gS, float* __restrict__ gS2){
  const int b = blockIdx.x, tid = threadIdx.x;
  __shared__ float sxl[15*256];
  __shared__ float s_deg[15], s_dinv[15], s_norm[71];
  __shared__ int   s_cnt[15], s_start[16], s_fill[15], s_srcl[71];
  if (tid < 15){ s_deg[tid] = 0.f; s_cnt[tid] = 0; s_fill[tid] = 0; }
  #pragma unroll
  for (int n = 0; n < 15; ++n)
    sxl[n*256 + tid] = xl[(size_t)(b*15 + n)*256 + tid];
  __syncthreads();
  int se = 0, de = 0; float we = 0.f;
  if (tid < 71){
    if (tid < 56){ se = ei[tid]; de = ei[56 + tid]; we = ew[tid]; }
    else         { se = tid - 56; de = tid - 56; we = 1.0f; }
    atomicAdd(&s_deg[de], we);
    atomicAdd(&s_cnt[de], 1);
  }
  __syncthreads();
  if (tid < 15) s_dinv[tid] = s_deg[tid] > 0.f ? rsqrtf(s_deg[tid]) : 0.f;
  if (tid == 0){
    int a = 0;
    for (int n = 0; n < 15; ++n){ s_start[n] = a; a += s_cnt[n]; }
    s_start[15] = a;
  }
  __syncthreads();
  if (tid < 71){
    float nrm = s_dinv[se]*we*s_dinv[de];
    int pos = s_start[de] + atomicAdd(&s_fill[de], 1);
    s_srcl[pos] = se; s_norm[pos] = nrm;
  }
  __syncthreads();
  const float gb = gcn_b[tid];
  for (int n = 0; n < 15; ++n){
    float acc = gb;
    const int e0 = s_start[n], e1 = s_start[n+1];
    for (int idx = e0; idx < e1; ++idx)
      acc += s_norm[idx]*sxl[s_srcl[idx]*256 + tid];
    Tpre[(size_t)(b*15 + n)*256 + tid] = acc;
    atomicAdd(&gS [n*256 + tid], acc);
    atomicAdd(&gS2[n*256 + tid], acc*acc);
  }
}

// ---------------------------------------------------------------------------
// Kernel 4: GraphNorm (stats from gS/gS2) + lin1-add + ELU + pool + head
// ---------------------------------------------------------------------------
__global__ void __launch_bounds__(256) finalize_k(
    const float* __restrict__ Tpre, const float* __restrict__ l1,
    const float* __restrict__ gS, const float* __restrict__ gS2,
    const float* __restrict__ gn_ms, const float* __restrict__ gn_w,
    const float* __restrict__ gn_b, const float* __restrict__ lin1_b,
    const float* __restrict__ out_w, const float* __restrict__ out_b,
    float* __restrict__ dout){
  const int b = blockIdx.x, tid = threadIdx.x;
  __shared__ float spool[256], spart[256];
  const float gnb = gn_b[tid], lb = lin1_b[tid];
  const float gms = gn_ms[tid], gwc = gn_w[tid];
  float acc = 0.f;
  #pragma unroll
  for (int n = 0; n < 15; ++n){
    const float s  = gS [n*256 + tid];
    const float s2 = gS2[n*256 + tid];
    const float mean = s*(1.f/128.f);
    const float mo   = mean*gms;
    float var = s2*(1.f/128.f) - 2.f*mo*mean + mo*mo;
    var = fmaxf(var, 0.f);
    const float scal = gwc*rsqrtf(var + 1e-5f);
    float t = (Tpre[(size_t)(b*15 + n)*256 + tid] - mo)*scal
              + gnb + l1[(size_t)(b*15 + n)*256 + tid] + lb;
    t = t > 0.f ? t : (__expf(t) - 1.f);   // ELU(alpha=1)
    acc += t;
  }
  const float pool = acc*(1.f/15.f);
  dout[b*256 + tid] = pool;
  spool[tid] = pool;
  __syncthreads();
  const int j = tid >> 4, q = tid & 15;
  float s = 0.f;
  for (int i = 0; i < 16; ++i){
    int cc = q + i*16;
    s += spool[cc]*out_w[j*256 + cc];
  }
  spart[tid] = s;
  __syncthreads();
  if (tid < 16){
    float tot = out_b[tid];
    #pragma unroll
    for (int i = 0; i < 16; ++i) tot += spart[tid*16 + i];
    dout[32768 + b*16 + tid] = tot;
  }
}

// ---------------------------------------------------------------------------
extern "C" void kernel_launch(void* const* d_in, const int* in_sizes, int n_in,
                              void* d_out, int out_size, void* d_ws, size_t ws_size,
                              hipStream_t stream){
  (void)in_sizes; (void)n_in; (void)out_size; (void)ws_size;
  const float* X    = (const float*)d_in[0];
  const int*   ei   = (const int*)d_in[1];
  const float* ew   = (const float*)d_in[2];
  const float* w1   = (const float*)d_in[3];
  const float* b1   = (const float*)d_in[4];
  const float* w2   = (const float*)d_in[5];
  const float* b2   = (const float*)d_in[6];
  const float* w3   = (const float*)d_in[7];
  const float* b3   = (const float*)d_in[8];
  const float* gw   = (const float*)d_in[9];
  const float* gb   = (const float*)d_in[10];
  const float* lw   = (const float*)d_in[11];
  const float* lb   = (const float*)d_in[12];
  const float* gnw  = (const float*)d_in[13];
  const float* gnb  = (const float*)d_in[14];
  const float* gnms = (const float*)d_in[15];
  const float* ow   = (const float*)d_in[16];
  const float* ob   = (const float*)d_in[17];

  char* ws = (char*)d_ws;
  u16*   h3p  = (u16*)(ws + 0);              //  7,372,800 B
  u16*   gwp  = (u16*)(ws + 7372800);        //    983,040 B (491,520 u16)
  u16*   Xb   = (u16*)(ws + 8355840);        //  7,372,800 B
  u16*   lwb  = (u16*)(ws + 15728640);       //    983,040 B (491,520 u16)
  float* xl   = (float*)(ws + 16711680);     //  1,966,080 B
  float* l1   = (float*)(ws + 18677760);     //  1,966,080 B
  float* gS   = (float*)(ws + 20643840);     //     15,360 B
  float* gS2  = (float*)(ws + 20659200);     //     15,360 B (end 20,674,560)
  float* Tpre = (float*)(ws + 0);            // reuse h3p (dead after gemm)

  fused_conv<<<dim3(16, 16, 15), dim3(256), 0, stream>>>(X, w1, b1, w2, b2, w3, b3,
                                                         h3p, Xb, lw, lwb, gw, gwp);
  gemm_nt   <<<dim3(30, 4, 2),   dim3(256), 0, stream>>>(Xb, lwb, l1, h3p, gwp, xl, gS);
  gcn_agg   <<<dim3(128),        dim3(256), 0, stream>>>(xl, ei, ew, gb, Tpre, gS, gS2);
  finalize_k<<<dim3(128),        dim3(256), 0, stream>>>(Tpre, l1, gS, gS2,
                                                         gnms, gnw, gnb, lb, ow, ob,
                                                         (float*)d_out);
}

// Round 15
// 198.072 us; speedup vs baseline: 1.0459x; 1.0459x over previous
//
#include <hip/hip_runtime.h>

typedef unsigned short u16;
typedef unsigned int   u32;

typedef short shortx8   __attribute__((ext_vector_type(8)));
typedef float floatx4   __attribute__((ext_vector_type(4)));
typedef float floatx16  __attribute__((ext_vector_type(16)));
typedef u32   uintx4    __attribute__((ext_vector_type(4)));

typedef u32     u32a     __attribute__((may_alias));
typedef uintx4  uintx4a  __attribute__((may_alias));
typedef shortx8 shortx8a __attribute__((may_alias));

// accurate round-to-nearest-even (weights)
__device__ __forceinline__ u16 f2bf(float f){
  union { float f; u32 i; } v; v.f = f;
  return (u16)((v.i + 0x7fffu + ((v.i >> 16) & 1u)) >> 16);
}
// fast round-half-up (scalar hot path; max 0.5 ulp)
__device__ __forceinline__ u16 f2bf_fast(float f){
  union { float f; u32 i; } v; v.f = f;
  return (u16)((v.i + 0x8000u) >> 16);
}
// pack two bf16 via v_perm (3 VALU ops) — fallback
__device__ __forceinline__ u32 pack2(float lo, float hi){
  union { float f; u32 i; } a, b; a.f = lo; b.f = hi;
  return __builtin_amdgcn_perm(b.i + 0x8000u, a.i + 0x8000u, 0x07060302u);
}
// packed f32->bf16 convert: 1 VALU op on gfx950 (v_cvt_pk_bf16_f32), RNE
__device__ __forceinline__ u32 cvtpk2(float lo, float hi){
#if __has_builtin(__builtin_amdgcn_cvt_pk_bf16_f32)
  auto pv = __builtin_amdgcn_cvt_pk_bf16_f32(lo, hi);
  if constexpr (sizeof(pv) == 4){
    u32 out; __builtin_memcpy(&out, &pv, 4); return out;
  } else {
    return pack2(lo, hi);
  }
#else
  return pack2(lo, hi);
#endif
}
__device__ __forceinline__ float lrelu(float v){ return fmaxf(v, 0.01f*v); }

// ---------------------------------------------------------------------------
// Kernel 1: fused conv1 (VALU) -> conv2 (MFMA 32x32x16) -> conv3 (MFMA
// 16x16x32). ROUND-13 CONFIGURATION (session best, 198.8 µs) — reverted
// after round-14's double-buffer pipeline regressed (LDS 25.6->43 KB cut
// occupancy 39->30%, erasing the barrier savings).
// Two t-tiles per block (120 conv3 outputs); 256-thread blocks = 2
// wave-pairs; per-pair h1/h2 LDS slots reused across the 8 (bb x tt)
// phases, each phase protected by the proven 2-barrier structure
// (cross-lane LDS handoffs need __syncthreads as compiler fence).
// Emits Xb during staging; absorbs prep (256 elements per block, exact:
// 3840 blocks x 256 = 983,040).
// grid (16 t-pairs, 16 b-groups, 15 nodes), block 256 (4 waves = 2 pairs).
// ---------------------------------------------------------------------------
__global__ void __launch_bounds__(256, 4) fused_conv(
    const float* __restrict__ X,
    const float* __restrict__ w1, const float* __restrict__ b1,
    const float* __restrict__ w2, const float* __restrict__ b2,
    const float* __restrict__ w3, const float* __restrict__ b3,
    u16* __restrict__ h3p, u16* __restrict__ Xb,
    const float* __restrict__ lw, u16* __restrict__ lwb,
    const float* __restrict__ gw, u16* __restrict__ gwp){
  const int tid  = threadIdx.x;
  const int node = blockIdx.z;
  const int p0   = blockIdx.x * 120;
  const int b0   = blockIdx.y * 8;

  __shared__ __attribute__((aligned(16))) u16 sH1[2*1632];  // per-pair [68][24]
  __shared__ __attribute__((aligned(16))) u16 sH2[2*2720];  // per-pair [68][40]
  __shared__ __attribute__((aligned(16))) u16 sW2f[2560];   // [tap][kh][oc32][j8]
  __shared__ __attribute__((aligned(16))) u16 sW3f[160];    // [tap][ic32]
  __shared__ u16 sXb[8*136];                                // bf16 X window (120+16)
  __shared__ float sW1[80], sB1[16], sB2[32];

  // ---- distributed prep: 256 elements per block, exact coverage ----
  {
    const int bid = blockIdx.x + 16*(blockIdx.y + 16*blockIdx.z);  // 0..3839
    int gid = bid*256 + tid;                   // 0..983039
    if (gid < 491520){
      lwb[gid] = f2bf(lw[gid]);                // lin1_w: 256*1920 elements
    } else {
      int g2 = gid - 491520;                   // 0..491519 (gwp elements)
      int row = g2 / 1920;                     // 0..255
      int col = g2 - row*1920;
      gwp[g2] = (col < 1908) ? f2bf(gw[row*1908 + col]) : (u16)0;
    }
  }

  // ---- staging ----
  {
    const int bls = tid >> 5, i0 = tid & 31;   // 8 batches x 32 threads
    const float* xrow = X  + (size_t)((b0 + bls)*15 + node)*1920;
    u16*        xbrow = Xb + (size_t)((b0 + bls)*15 + node)*1920;
    #pragma unroll
    for (int u = 0; u < 5; ++u){
      int i = i0 + 32*u;
      if (i < 136){
        int g = p0 + i;
        float xv = (g < 1920) ? xrow[g] : 0.f;
        u16 xb = f2bf_fast(xv);
        sXb[bls*136 + i] = xb;
        if (i < 120) xbrow[g] = xb;   // i<120 => g<1920 always
      }
    }
    // w2 into 32x32 A-frag order: idx = ((tap*2 + kh)*32 + oc)*8 + j
    #pragma unroll
    for (int u = 0; u < 10; ++u){
      int d = tid + 256*u;
      int j = d & 7, oc = (d >> 3) & 31, kh = (d >> 8) & 1, tap = d >> 9; // 0..4
      sW2f[d] = f2bf(w2[node*2560 + (oc*16 + kh*8 + j)*5 + tap]);
    }
    if (tid < 160){
      int icc = tid / 5, tp = tid - 5*icc;
      sW3f[tp*32 + icc] = f2bf(w3[node*160 + tid]);
    }
    if (tid < 80) sW1[tid] = w1[node*80 + tid];
    if (tid < 16) sB1[tid] = b1[node*16 + tid];
    if (tid < 32) sB2[tid] = b2[node*32 + tid];
  }
  __syncthreads();

  const int w = tid >> 6, lane = tid & 63;
  const int pw = w >> 1, ph = w & 1;          // pair index (0..1) / pair half
  const int m = lane & 15, quad = lane >> 4;  // 16x16 roles
  const int t32 = lane & 31, kh = lane >> 5;  // 32x32 roles (kh = k-half)

  // conv2 A-frags (32x32x16): A[m=oc=lane&31][k=kh*8+j]
  shortx8 a2t[5];
  #pragma unroll
  for (int tap = 0; tap < 5; ++tap)
    a2t[tap] = *(const shortx8a*)&sW2f[((tap*2 + kh)*32 + t32)*8];

  // conv2 bias per accumulator reg: row(oc) = (r&3) + 8*(r>>2) + 4*kh
  float biasr[16];
  #pragma unroll
  for (int r = 0; r < 16; ++r)
    biasr[r] = sB2[(r&3) + 8*(r>>2) + 4*kh];

  // conv3 A-frags (16x16x32): only row m=0 nonzero
  shortx8 a3[5];
  {
    const shortx8 zv = {0,0,0,0,0,0,0,0};
    #pragma unroll
    for (int tp = 0; tp < 5; ++tp){
      shortx8 t = *(const shortx8a*)&sW3f[tp*32 + quad*8];
      a3[tp] = (m == 0) ? t : zv;
    }
  }
  const float b3v = b3[node];

  u16* h1w = sH1 + pw*1632;
  u16* h2w = sH2 + pw*2720;
  // zero sH2 tail rows 64..67 (conv2 writes rows 0..63; conv3 reads to 67)
  for (int i = lane + ph*64; i < 160; i += 128) h2w[2560 + i] = 0;

  // conv1 per-lane role: 8 ic-pairs x 16 pair-wide t-chunks of 5
  const int c1ic = (lane & 7)*2;
  const int cc   = (lane >> 3) + ph*8;   // 0..15
  const int t0c  = cc*5;                 // 0,5,...,75 (chunks >=68 idle)
  float wa[5], wb[5];
  #pragma unroll
  for (int k = 0; k < 5; ++k){ wa[k] = sW1[c1ic*5 + k]; wb[k] = sW1[c1ic*5 + 5 + k]; }
  const float ba = sB1[c1ic], bbv = sB1[c1ic + 1];

  for (int bb = 0; bb < 4; ++bb){
    const int bl = pw + bb*2;   // 0..7
    const int rg = (b0 + bl)*15 + node;

    #pragma unroll
    for (int tt = 0; tt < 2; ++tt){
      const int p = p0 + tt*60;

      // ---- conv1 (VALU): this pair's batch, chunk of 5 t per lane ----
      if (t0c < 68){
        const u16* xr = sXb + bl*136 + tt*60;
        union { u32 i; float f; } cv;
        float xw[5];
        #pragma unroll
        for (int k = 0; k < 4; ++k){ cv.i = ((u32)xr[t0c+k]) << 16; xw[k] = cv.f; }
        #pragma unroll
        for (int i = 0; i < 5; ++i){
          const int t = t0c + i;
          cv.i = ((u32)xr[t + 4]) << 16; xw[4] = cv.f;   // max idx 60+73=133 < 136
          float va = ba  + wa[0]*xw[0] + wa[1]*xw[1] + wa[2]*xw[2] + wa[3]*xw[3] + wa[4]*xw[4];
          float vb = bbv + wb[0]*xw[0] + wb[1]*xw[1] + wb[2]*xw[2] + wb[3]*xw[3] + wb[4]*xw[4];
          va = lrelu(va); vb = lrelu(vb);
          if (t < 68) *(u32a*)(h1w + t*24 + c1ic) = cvtpk2(va, vb);
          xw[0] = xw[1]; xw[1] = xw[2]; xw[2] = xw[3]; xw[3] = xw[4];
        }
      }
      __syncthreads();   // conv1 writes -> conv2 reads (cross-lane LDS handoff)

      // ---- conv2 (32x32x16): tile nt=ph, 5 tap MFMAs, bias in acc ----
      {
        const int t0 = ph*32;
        floatx16 acc;
        #pragma unroll
        for (int r = 0; r < 16; ++r) acc[r] = biasr[r];
        #pragma unroll
        for (int tap = 0; tap < 5; ++tap){
          shortx8 bfr = *(const shortx8a*)(h1w + (t0 + t32 + tap)*24 + kh*8);
          acc = __builtin_amdgcn_mfma_f32_32x32x16_bf16(a2t[tap], bfr, acc, 0, 0, 0);
        }
        // D: col(t)=lane&31, row(oc)=(r&3)+8*(r>>2)+4*kh; r-pairs = oc pairs
        u16* dst = h2w + (t0 + t32)*40;
        #pragma unroll
        for (int r = 0; r < 16; r += 2){
          float v0 = lrelu(acc[r]);
          float v1 = lrelu(acc[r+1]);
          const int oc0 = (r&3) + 8*(r>>2) + 4*kh;
          *(u32a*)(dst + oc0) = cvtpk2(v0, v1);
        }
      }
      __syncthreads();   // conv2 writes -> conv3 reads (cross-lane LDS handoff)

      // ---- conv3 (16x16x32): tiles {2ph, 2ph+1}, 5 tap MFMAs; D row 0 ----
      #pragma unroll
      for (int i = 0; i < 2; ++i){
        const int nt = 2*ph + i;
        floatx4 acc3 = {0.f,0.f,0.f,0.f};
        if (lane < 16) acc3[0] = b3v;
        #pragma unroll
        for (int tp = 0; tp < 5; ++tp){
          shortx8 bfr = *(const shortx8a*)(h2w + (nt*16 + m + tp)*40 + quad*8);
          acc3 = __builtin_amdgcn_mfma_f32_16x16x32_bf16(a3[tp], bfr, acc3, 0, 0, 0);
        }
        const int tl = nt*16 + lane;
        if (lane < 16 && tl < 60){
          const int t3 = p + tl;           // max 15*120+60+59 = 1919 < 1920
          float v = lrelu(acc3[0]);
          h3p[(size_t)rg*1920 + t3] = (t3 < 1908) ? f2bf_fast(v) : (u16)0;
        }
      }
    }
  }
}

// ---------------------------------------------------------------------------
// Kernel 2: NT GEMM  O[1920][256] = A[1920][1920] * B[256][1920]^T (full K,
// plain stores). grid (30,4,2): z = job (0: Xb*lwb->l1, 1: h3p*gwp->xl).
// K-step 64; LDS stride 88 u16. Block (0,0,0) also zeroes the 30KB
// GraphNorm stats buffer (gS/gS2) consumed by gcn_agg/finalize.
// ---------------------------------------------------------------------------
__global__ void __launch_bounds__(256) gemm_nt(
    const u16* __restrict__ A0, const u16* __restrict__ B0, float* __restrict__ O0,
    const u16* __restrict__ A1, const u16* __restrict__ B1, float* __restrict__ O1,
    float* __restrict__ gZ){
  const int job = blockIdx.z;
  const u16* A; const u16* Bm; float* O;
  if (job == 0){ A = A0; Bm = B0; O = O0; } else { A = A1; Bm = B1; O = O1; }
  __shared__ __attribute__((aligned(16))) u16 sA[64*88];
  __shared__ __attribute__((aligned(16))) u16 sB[64*88];
  const int tid = threadIdx.x;
  if (blockIdx.x == 0 && blockIdx.y == 0 && job == 0){
    #pragma unroll
    for (int u = 0; u < 30; ++u) gZ[tid + 256*u] = 0.f;
  }
  const int m0 = blockIdx.x*64, n0 = blockIdx.y*64;
  const int row = tid >> 2, kc = tid & 3;
  const int w = tid >> 6, lane = tid & 63;
  const int m = lane & 15, quad = lane >> 4;
  const int mo = (w & 1)*32, no = (w >> 1)*32;
  floatx4 acc[2][2];
  #pragma unroll
  for (int i = 0; i < 2; ++i)
    #pragma unroll
    for (int j = 0; j < 2; ++j)
      #pragma unroll
      for (int r = 0; r < 4; ++r) acc[i][j][r] = 0.f;

  const u16* ap = A  + (size_t)(m0 + row)*1920 + kc*8;
  const u16* bp = Bm + (size_t)(n0 + row)*1920 + kc*8;
  for (int kt = 0; kt < 30; ++kt){
    uintx4 va0 = *(const uintx4a*)ap;
    uintx4 va1 = *(const uintx4a*)(ap + 32);
    uintx4 vb0 = *(const uintx4a*)bp;
    uintx4 vb1 = *(const uintx4a*)(bp + 32);
    ap += 64; bp += 64;
    *(uintx4a*)&sA[row*88 + kc*8]      = va0;
    *(uintx4a*)&sA[row*88 + 32 + kc*8] = va1;
    *(uintx4a*)&sB[row*88 + kc*8]      = vb0;
    *(uintx4a*)&sB[row*88 + 32 + kc*8] = vb1;
    __syncthreads();
    #pragma unroll
    for (int ks = 0; ks < 64; ks += 32){
      const shortx8 af0 = *(const shortx8a*)&sA[(mo      + m)*88 + ks + quad*8];
      const shortx8 af1 = *(const shortx8a*)&sA[(mo + 16 + m)*88 + ks + quad*8];
      const shortx8 bf0 = *(const shortx8a*)&sB[(no      + m)*88 + ks + quad*8];
      const shortx8 bf1 = *(const shortx8a*)&sB[(no + 16 + m)*88 + ks + quad*8];
      acc[0][0] = __builtin_amdgcn_mfma_f32_16x16x32_bf16(af0, bf0, acc[0][0], 0, 0, 0);
      acc[0][1] = __builtin_amdgcn_mfma_f32_16x16x32_bf16(af0, bf1, acc[0][1], 0, 0, 0);
      acc[1][0] = __builtin_amdgcn_mfma_f32_16x16x32_bf16(af1, bf0, acc[1][0], 0, 0, 0);
      acc[1][1] = __builtin_amdgcn_mfma_f32_16x16x32_bf16(af1, bf1, acc[1][1], 0, 0, 0);
    }
    __syncthreads();
  }
  #pragma unroll
  for (int mi = 0; mi < 2; ++mi)
    #pragma unroll
    for (int ni = 0; ni < 2; ++ni)
      #pragma unroll
      for (int r = 0; r < 4; ++r){
        int rr = m0 + mo + mi*16 + quad*4 + r;
        int cc = n0 + no + ni*16 + m;
        O[(size_t)rr*256 + cc] = acc[mi][ni][r];
      }
}

// ---------------------------------------------------------------------------
// Kernel 3: GCN aggregation + bias, plus per-(n,c) GraphNorm stat
// accumulation (atomicAdd of T and T^2 into gS/gS2, zeroed by gemm_nt).
// ---------------------------------------------------------------------------
__global__ void __launch_bounds__(256) gcn_agg(
    const float* __restrict__ xl, const int* __restrict__ ei,
    const float* __restrict__ ew, const float* __restrict__ gcn_b,
    float* __restrict__ Tpre, float* __restrict__ gS, float* __restrict__ gS2){
  const int b = blockIdx.x, tid = threadIdx.x;
  __shared__ float sxl[15*256];
  __shared__ float s_deg[15], s_dinv[15], s_norm[71];
  __shared__ int   s_cnt[15], s_start[16], s_fill[15], s_srcl[71];
  if (tid < 15){ s_deg[tid] = 0.f; s_cnt[tid] = 0; s_fill[tid] = 0; }
  #pragma unroll
  for (int n = 0; n < 15; ++n)
    sxl[n*256 + tid] = xl[(size_t)(b*15 + n)*256 + tid];
  __syncthreads();
  int se = 0, de = 0; float we = 0.f;
  if (tid < 71){
    if (tid < 56){ se = ei[tid]; de = ei[56 + tid]; we = ew[tid]; }
    else         { se = tid - 56; de = tid - 56; we = 1.0f; }
    atomicAdd(&s_deg[de], we);
    atomicAdd(&s_cnt[de], 1);
  }
  __syncthreads();
  if (tid < 15) s_dinv[tid] = s_deg[tid] > 0.f ? rsqrtf(s_deg[tid]) : 0.f;
  if (tid == 0){
    int a = 0;
    for (int n = 0; n < 15; ++n){ s_start[n] = a; a += s_cnt[n]; }
    s_start[15] = a;
  }
  __syncthreads();
  if (tid < 71){
    float nrm = s_dinv[se]*we*s_dinv[de];
    int pos = s_start[de] + atomicAdd(&s_fill[de], 1);
    s_srcl[pos] = se; s_norm[pos] = nrm;
  }
  __syncthreads();
  const float gb = gcn_b[tid];
  for (int n = 0; n < 15; ++n){
    float acc = gb;
    const int e0 = s_start[n], e1 = s_start[n+1];
    for (int idx = e0; idx < e1; ++idx)
      acc += s_norm[idx]*sxl[s_srcl[idx]*256 + tid];
    Tpre[(size_t)(b*15 + n)*256 + tid] = acc;
    atomicAdd(&gS [n*256 + tid], acc);
    atomicAdd(&gS2[n*256 + tid], acc*acc);
  }
}

// ---------------------------------------------------------------------------
// Kernel 4: GraphNorm (stats from gS/gS2) + lin1-add + ELU + pool + head
// ---------------------------------------------------------------------------
__global__ void __launch_bounds__(256) finalize_k(
    const float* __restrict__ Tpre, const float* __restrict__ l1,
    const float* __restrict__ gS, const float* __restrict__ gS2,
    const float* __restrict__ gn_ms, const float* __restrict__ gn_w,
    const float* __restrict__ gn_b, const float* __restrict__ lin1_b,
    const float* __restrict__ out_w, const float* __restrict__ out_b,
    float* __restrict__ dout){
  const int b = blockIdx.x, tid = threadIdx.x;
  __shared__ float spool[256], spart[256];
  const float gnb = gn_b[tid], lb = lin1_b[tid];
  const float gms = gn_ms[tid], gwc = gn_w[tid];
  float acc = 0.f;
  #pragma unroll
  for (int n = 0; n < 15; ++n){
    const float s  = gS [n*256 + tid];
    const float s2 = gS2[n*256 + tid];
    const float mean = s*(1.f/128.f);
    const float mo   = mean*gms;
    float var = s2*(1.f/128.f) - 2.f*mo*mean + mo*mo;
    var = fmaxf(var, 0.f);
    const float scal = gwc*rsqrtf(var + 1e-5f);
    float t = (Tpre[(size_t)(b*15 + n)*256 + tid] - mo)*scal
              + gnb + l1[(size_t)(b*15 + n)*256 + tid] + lb;
    t = t > 0.f ? t : (__expf(t) - 1.f);   // ELU(alpha=1)
    acc += t;
  }
  const float pool = acc*(1.f/15.f);
  dout[b*256 + tid] = pool;
  spool[tid] = pool;
  __syncthreads();
  const int j = tid >> 4, q = tid & 15;
  float s = 0.f;
  for (int i = 0; i < 16; ++i){
    int cc = q + i*16;
    s += spool[cc]*out_w[j*256 + cc];
  }
  spart[tid] = s;
  __syncthreads();
  if (tid < 16){
    float tot = out_b[tid];
    #pragma unroll
    for (int i = 0; i < 16; ++i) tot += spart[tid*16 + i];
    dout[32768 + b*16 + tid] = tot;
  }
}

// ---------------------------------------------------------------------------
extern "C" void kernel_launch(void* const* d_in, const int* in_sizes, int n_in,
                              void* d_out, int out_size, void* d_ws, size_t ws_size,
                              hipStream_t stream){
  (void)in_sizes; (void)n_in; (void)out_size; (void)ws_size;
  const float* X    = (const float*)d_in[0];
  const int*   ei   = (const int*)d_in[1];
  const float* ew   = (const float*)d_in[2];
  const float* w1   = (const float*)d_in[3];
  const float* b1   = (const float*)d_in[4];
  const float* w2   = (const float*)d_in[5];
  const float* b2   = (const float*)d_in[6];
  const float* w3   = (const float*)d_in[7];
  const float* b3   = (const float*)d_in[8];
  const float* gw   = (const float*)d_in[9];
  const float* gb   = (const float*)d_in[10];
  const float* lw   = (const float*)d_in[11];
  const float* lb   = (const float*)d_in[12];
  const float* gnw  = (const float*)d_in[13];
  const float* gnb  = (const float*)d_in[14];
  const float* gnms = (const float*)d_in[15];
  const float* ow   = (const float*)d_in[16];
  const float* ob   = (const float*)d_in[17];

  char* ws = (char*)d_ws;
  u16*   h3p  = (u16*)(ws + 0);              //  7,372,800 B
  u16*   gwp  = (u16*)(ws + 7372800);        //    983,040 B (491,520 u16)
  u16*   Xb   = (u16*)(ws + 8355840);        //  7,372,800 B
  u16*   lwb  = (u16*)(ws + 15728640);       //    983,040 B (491,520 u16)
  float* xl   = (float*)(ws + 16711680);     //  1,966,080 B
  float* l1   = (float*)(ws + 18677760);     //  1,966,080 B
  float* gS   = (float*)(ws + 20643840);     //     15,360 B
  float* gS2  = (float*)(ws + 20659200);     //     15,360 B (end 20,674,560)
  float* Tpre = (float*)(ws + 0);            // reuse h3p (dead after gemm)

  fused_conv<<<dim3(16, 16, 15), dim3(256), 0, stream>>>(X, w1, b1, w2, b2, w3, b3,
                                                         h3p, Xb, lw, lwb, gw, gwp);
  gemm_nt   <<<dim3(30, 4, 2),   dim3(256), 0, stream>>>(Xb, lwb, l1, h3p, gwp, xl, gS);
  gcn_agg   <<<dim3(128),        dim3(256), 0, stream>>>(xl, ei, ew, gb, Tpre, gS, gS2);
  finalize_k<<<dim3(128),        dim3(256), 0, stream>>>(Tpre, l1, gS, gS2,
                                                         gnms, gnw, gnb, lb, ow, ob,
                                                         (float*)d_out);
}